// Round 8
// baseline (388.039 us; speedup 1.0000x reference)
//
#include <hip/hip_runtime.h>
#include <hip/hip_bf16.h>

typedef __attribute__((ext_vector_type(4))) float f32x4;
typedef __attribute__((ext_vector_type(4))) uint u32x4;
typedef __attribute__((ext_vector_type(8))) short bf16x8;

#define M_TOTAL 32768
#define N_TOTAL 1024
#define K_TOTAL 1024

__device__ __forceinline__ uint pk2(float a, float b) {
  __hip_bfloat162 h = __float22bfloat162_rn(make_float2(a, b));  // v_cvt_pk_bf16_f32
  uint u;
  __builtin_memcpy(&u, &h, 4);
  return u;
}

// Non-draining barrier (T4): ds visibility via lgkmcnt(0); global prefetches
// stay in flight across it (counted vmcnt at consumption). Rule #18 pinning.
#define SOFT_BARRIER() do {                                                   \
    __builtin_amdgcn_sched_barrier(0);                                        \
    asm volatile("s_waitcnt lgkmcnt(0)" ::: "memory");                        \
    __builtin_amdgcn_s_barrier();                                             \
    __builtin_amdgcn_sched_barrier(0);                                        \
  } while (0)

// ===========================================================================
// Pre-kernel: convert 4x 256x256 f32 S-matrices to fragment-major bf16 in ws.
// Fragment (si, cb, kb): 64 lanes x 16B contiguous; lane l holds
// S[cb*16 + (l&15)][kb*32 + (l>>4)*8 .. +7]  (matches MFMA frag layout).
// Verified correct in round 7 (absmax 0.03125).
// ===========================================================================
__global__ __launch_bounds__(256) void conv_b(
    const float* __restrict__ Rm, const float* __restrict__ Im,
    const float* __restrict__ Jm, const float* __restrict__ Km,
    ushort* __restrict__ ws)
{
  const int slot = blockIdx.x * 256 + threadIdx.x;  // 0..32767
  const int lane = slot & 63;
  const int kb = (slot >> 6) & 7;
  const int cb = (slot >> 9) & 15;
  const int si = slot >> 13;
  const float* S = (si == 0) ? Rm : (si == 1) ? Im : (si == 2) ? Jm : Km;
  const float* p = S + (cb * 16 + (lane & 15)) * 256 + kb * 32 + (lane >> 4) * 8;
  f32x4 lo = *(const f32x4*)p;
  f32x4 hi = *(const f32x4*)(p + 4);
  u32x4 v;
  v[0] = pk2(lo[0], lo[1]); v[1] = pk2(lo[2], lo[3]);
  v[2] = pk2(hi[0], hi[1]); v[3] = pk2(hi[2], hi[3]);
  *(u32x4*)(ws + (size_t)slot * 8) = v;
}

// ===========================================================================
// Main kernel v3: 128x256 block tile, 8 waves (2 row-groups x 4 col-groups),
// wave tile 64x64 (acc = 64 VGPR -> 4 waves/SIMD, 2 blocks/CU).
// A: f32 -> reg -> cvt -> swizzled LDS (32 KB dbuf). B: frag-direct from ws.
// ===========================================================================
#define BM3 128
#define BN3 256
#define BK3 64
#define NT3 512
#define NSTEPS3 (K_TOTAL / BK3)

#define LOAD_A3(kk) do {                                                      \
    _Pragma("unroll")                                                         \
    for (int cc = 0; cc < 2; ++cc) {                                          \
      const float* pa_ = X + (size_t)(m0 + r0 + 64 * cc) * K_TOTAL + (kk) + k0;\
      rA[2 * cc]     = *(const f32x4*)pa_;                                    \
      rA[2 * cc + 1] = *(const f32x4*)(pa_ + 4);                              \
    }                                                                         \
  } while (0)

#define COMMIT_A3(dst) do {                                                   \
    _Pragma("unroll")                                                         \
    for (int cc = 0; cc < 2; ++cc) {                                          \
      u32x4 va_;                                                              \
      va_[0] = pk2(rA[2 * cc][0], rA[2 * cc][1]);                             \
      va_[1] = pk2(rA[2 * cc][2], rA[2 * cc][3]);                             \
      va_[2] = pk2(rA[2 * cc + 1][0], rA[2 * cc + 1][1]);                     \
      va_[3] = pk2(rA[2 * cc + 1][2], rA[2 * cc + 1][3]);                     \
      *(u32x4*)((dst) + sbase + 8192 * cc) = va_;                             \
    }                                                                         \
  } while (0)

// Load 8 B-frags (2 ks x 4 ni) for K-step kk; sign via bf16 sign-bit XOR
// (block-uniform; commutes with RNE cvt -> bit-identical numerics).
#define LOAD_B3(kk) do {                                                      \
    const int bsel_ = (kk) >> 8;                                              \
    const int si_ = a_idx ^ bsel_;                                            \
    const int kbq_ = ((kk) & 255) >> 5;                                       \
    const ushort* fb_ = WS + ((size_t)((si_ * 16 + wc4) * 8 + kbq_)) * 512    \
                        + lane * 8;                                           \
    _Pragma("unroll")                                                         \
    for (int ks = 0; ks < 2; ++ks)                                            \
      _Pragma("unroll")                                                       \
      for (int ni = 0; ni < 4; ++ni)                                          \
        bq[ks * 4 + ni] = *(const bf16x8*)(fb_ + (ni * 8 + ks) * 512);        \
    if ((0x284Eu >> ((a_idx << 2) | bsel_)) & 1u) {                           \
      _Pragma("unroll")                                                       \
      for (int f = 0; f < 8; ++f) {                                           \
        u32x4 u_ = __builtin_bit_cast(u32x4, bq[f]);                          \
        u_[0] ^= 0x80008000u; u_[1] ^= 0x80008000u;                           \
        u_[2] ^= 0x80008000u; u_[3] ^= 0x80008000u;                           \
        bq[f] = __builtin_bit_cast(bf16x8, u_);                               \
      }                                                                       \
    }                                                                         \
  } while (0)

#define COMPUTE3(src) do {                                                    \
    _Pragma("unroll")                                                         \
    for (int ks = 0; ks < 2; ++ks) {                                          \
      const int kb_ = (ks << 6) + fkb;                                        \
      _Pragma("unroll")                                                       \
      for (int mi = 0; mi < 4; ++mi) {                                        \
        const int row_ = frow_a0 + (mi << 4);                                 \
        bf16x8 af_ = *(const bf16x8*)((src) + row_ * (BK3 * 2)                \
                                      + (kb_ ^ ((row_ & 7) << 4)));           \
        _Pragma("unroll")                                                     \
        for (int ni = 0; ni < 4; ++ni)                                        \
          acc[mi][ni] = __builtin_amdgcn_mfma_f32_16x16x32_bf16(              \
              af_, bq[ks * 4 + ni], acc[mi][ni], 0, 0, 0);                    \
      }                                                                       \
    }                                                                         \
  } while (0)

__global__ __launch_bounds__(NT3, 4) void qlin_gemm3(
    const float* __restrict__ X, const ushort* __restrict__ WS,
    const float* __restrict__ bias, float* __restrict__ Y)
{
  // 1024 blocks = 256 m-blocks x 4 n-blocks; XCD-bijective swizzle
  // (1024%8==0), n fastest so an XCD chunk shares A-panels in its L2.
  const int per = ((M_TOTAL / BM3) * (N_TOTAL / BN3)) >> 3;  // 128
  const int bid = (int)blockIdx.x;
  const int swz = (bid & 7) * per + (bid >> 3);
  const int m0 = (swz >> 2) * BM3;
  const int nblk = swz & 3;
  const int n0 = nblk * BN3;
  const int a_idx = nblk;  // BN=256 -> a_idx == nblk; o_src == 0

  const int tid = (int)threadIdx.x;
  const int lane = tid & 63;
  const int wave = tid >> 6;
  const int wm = (wave >> 2) << 6;   // wave row origin: 0/64
  const int wn = (wave & 3) << 6;    // wave col origin: 0/64/128/192
  const int wc4 = (wave & 3) << 2;   // wave col-frag base (16-col units)

  __shared__ __align__(16) ushort smA[2 * BM3 * BK3];  // 32 KB dbuf
  char* const cS = (char*)smA;

  // A staging: thread stages 16 elems = 2 chunks of 8; rows r0 + 64*cc.
  const int r0 = tid >> 3;        // 0..63
  const int k0 = (tid & 7) << 3;  // 0..56
  const int sbase = r0 * (BK3 * 2) + ((k0 * 2) ^ ((r0 & 7) << 4));

  f32x4 rA[4];
  bf16x8 bq[8];
  f32x4 acc[4][4];
#pragma unroll
  for (int i = 0; i < 4; ++i)
#pragma unroll
    for (int j = 0; j < 4; ++j) acc[i][j] = (f32x4)(0.0f);

  const int frow_a0 = wm + (lane & 15);
  const int fkb = (lane >> 4) << 4;

  // prologue
  LOAD_A3(0);
  COMMIT_A3(cS);
  LOAD_A3(BK3);
  SOFT_BARRIER();

  // main loop: commit(k+1 from rA) -> LOAD_B(k) -> prefetch A(k+2) ->
  // compute(k) waits B at counted vmcnt (A prefetch stays in flight).
#pragma unroll 1
  for (int k = 0; k < NSTEPS3; ++k) {
    char* const rbuf = cS + ((k & 1) << 14);
    char* const wbuf = cS + (((k + 1) & 1) << 14);
    COMMIT_A3(wbuf);                              // cvt rA(k+1) -> LDS
    LOAD_B3(k * BK3);                             // 8 frag loads (L2)
    if (k + 2 < NSTEPS3) LOAD_A3((k + 2) * BK3);  // prefetch A(k+2)
    COMPUTE3(rbuf);                               // 8 ds_read + 32 MFMA
    SOFT_BARRIER();
  }

  // epilogue: C/D layout col = lane&15, row = (lane>>4)*4 + reg  [m89-verified]
#pragma unroll
  for (int ni = 0; ni < 4; ++ni) {
    const int col = n0 + wn + (ni << 4) + (lane & 15);
    const float bv = bias[col];
#pragma unroll
    for (int mi = 0; mi < 4; ++mi) {
      const int r0e = m0 + wm + (mi << 4) + ((lane >> 4) << 2);
#pragma unroll
      for (int j = 0; j < 4; ++j)
        Y[(size_t)(r0e + j) * N_TOTAL + col] = acc[mi][ni][j] + bv;
    }
  }
}

// ===========================================================================
// Fallback (proven round-6 kernel, 126 us) — used only if ws_size < 512 KB.
// ===========================================================================
#define BM 128
#define BN 128
#define BK 64
#define NTHREADS 256
#define NSTEPS (K_TOTAL / BK)

#define LOAD_TILE(kk) do {                                                    \
    const int si_ = a_idx ^ ((kk) >> 8);                                      \
    const float* Bsrc_ = (si_ == 0) ? Rm : (si_ == 1) ? Im                    \
                       : (si_ == 2) ? Jm : Km;                                \
    const int kloc_ = (kk) & 255;                                             \
    _Pragma("unroll")                                                         \
    for (int cc = 0; cc < 4; ++cc) {                                          \
      const float* pa_ = X + (size_t)(m0 + r0 + 32 * cc) * K_TOTAL + (kk) + k0;\
      rA[2 * cc]     = *(const f32x4*)pa_;                                    \
      rA[2 * cc + 1] = *(const f32x4*)(pa_ + 4);                              \
      const float* pb_ = Bsrc_ + (o_src + r0 + 32 * cc) * 256 + kloc_ + k0;   \
      rB[2 * cc]     = *(const f32x4*)pb_;                                    \
      rB[2 * cc + 1] = *(const f32x4*)(pb_ + 4);                              \
    }                                                                         \
  } while (0)

#define COMMIT_TILE(kk, dst) do {                                             \
    const uint neg_ = (0x284Eu >> ((a_idx << 2) | ((kk) >> 8))) & 1u;         \
    _Pragma("unroll")                                                         \
    for (int cc = 0; cc < 4; ++cc) {                                          \
      u32x4 va_;                                                              \
      va_[0] = pk2(rA[2 * cc][0], rA[2 * cc][1]);                             \
      va_[1] = pk2(rA[2 * cc][2], rA[2 * cc][3]);                             \
      va_[2] = pk2(rA[2 * cc + 1][0], rA[2 * cc + 1][1]);                     \
      va_[3] = pk2(rA[2 * cc + 1][2], rA[2 * cc + 1][3]);                     \
      *(u32x4*)((dst) + sbase + 4096 * cc) = va_;                             \
    }                                                                         \
    if (neg_) {                                                               \
      _Pragma("unroll")                                                       \
      for (int cc = 0; cc < 4; ++cc) {                                        \
        u32x4 vb_;                                                            \
        vb_[0] = pk2(-rB[2 * cc][0], -rB[2 * cc][1]);                         \
        vb_[1] = pk2(-rB[2 * cc][2], -rB[2 * cc][3]);                         \
        vb_[2] = pk2(-rB[2 * cc + 1][0], -rB[2 * cc + 1][1]);                 \
        vb_[3] = pk2(-rB[2 * cc + 1][2], -rB[2 * cc + 1][3]);                 \
        *(u32x4*)((dst) + 16384 + sbase + 4096 * cc) = vb_;                   \
      }                                                                       \
    } else {                                                                  \
      _Pragma("unroll")                                                       \
      for (int cc = 0; cc < 4; ++cc) {                                        \
        u32x4 vb_;                                                            \
        vb_[0] = pk2(rB[2 * cc][0], rB[2 * cc][1]);                           \
        vb_[1] = pk2(rB[2 * cc][2], rB[2 * cc][3]);                           \
        vb_[2] = pk2(rB[2 * cc + 1][0], rB[2 * cc + 1][1]);                   \
        vb_[3] = pk2(rB[2 * cc + 1][2], rB[2 * cc + 1][3]);                   \
        *(u32x4*)((dst) + 16384 + sbase + 4096 * cc) = vb_;                   \
      }                                                                       \
    }                                                                         \
  } while (0)

#define COMPUTE_TILE(src) do {                                                \
    _Pragma("unroll")                                                         \
    for (int ks = 0; ks < 2; ++ks) {                                          \
      const int kb_ = (ks << 6) + fkb;                                        \
      bf16x8 af_[4], bf_[4];                                                  \
      _Pragma("unroll")                                                       \
      for (int mi = 0; mi < 4; ++mi) {                                        \
        const int row_ = frow_a0 + (mi << 4);                                 \
        af_[mi] = *(const bf16x8*)((src) + row_ * (BK * 2)                    \
                                   + (kb_ ^ ((row_ & 7) << 4)));              \
      }                                                                       \
      _Pragma("unroll")                                                       \
      for (int ni = 0; ni < 4; ++ni) {                                        \
        const int row_ = frow_b0 + (ni << 4);                                 \
        bf_[ni] = *(const bf16x8*)((src) + 16384 + row_ * (BK * 2)            \
                                   + (kb_ ^ ((row_ & 7) << 4)));              \
      }                                                                       \
      _Pragma("unroll")                                                       \
      for (int mi = 0; mi < 4; ++mi)                                          \
        _Pragma("unroll")                                                     \
        for (int ni = 0; ni < 4; ++ni)                                        \
          acc[mi][ni] = __builtin_amdgcn_mfma_f32_16x16x32_bf16(              \
              af_[mi], bf_[ni], acc[mi][ni], 0, 0, 0);                        \
    }                                                                         \
  } while (0)

__global__ __launch_bounds__(NTHREADS, 2) void qlin_gemm(
    const float* __restrict__ X, const float* __restrict__ Rm,
    const float* __restrict__ Im, const float* __restrict__ Jm,
    const float* __restrict__ Km, const float* __restrict__ bias,
    float* __restrict__ Y)
{
  const int per = ((M_TOTAL / BM) * (N_TOTAL / BN)) >> 3;
  const int bid = (int)blockIdx.x;
  const int swz = (bid & 7) * per + (bid >> 3);
  const int m0 = (swz >> 3) * BM;
  const int n0 = (swz & 7) * BN;

  const int tid = (int)threadIdx.x;
  const int lane = tid & 63;
  const int wave = tid >> 6;
  const int wm = (wave >> 1) << 6;
  const int wn = (wave & 1) << 6;

  __shared__ __align__(16) ushort sm[2 * 2 * BM * BK];
  char* const cS = (char*)sm;

  const int a_idx = n0 >> 8;
  const int o_src = n0 & 255;

  const int r0 = tid >> 3;
  const int k0 = (tid & 7) << 3;
  const int sbase = r0 * (BK * 2) + ((k0 * 2) ^ ((r0 & 7) << 4));

  f32x4 rA[8], rB[8];
  f32x4 acc[4][4];
#pragma unroll
  for (int i = 0; i < 4; ++i)
#pragma unroll
    for (int j = 0; j < 4; ++j) acc[i][j] = (f32x4)(0.0f);

  const int frow_a0 = wm + (lane & 15);
  const int frow_b0 = wn + (lane & 15);
  const int fkb = (lane >> 4) << 4;

  LOAD_TILE(0);
  COMMIT_TILE(0, cS);
  LOAD_TILE(BK);
  SOFT_BARRIER();

#pragma unroll 1
  for (int k = 0; k < NSTEPS; ++k) {
    char* const rbuf = cS + ((k & 1) << 15);
    char* const wbuf = cS + (((k + 1) & 1) << 15);
    if (k + 1 < NSTEPS) COMMIT_TILE((k + 1) * BK, wbuf);
    if (k + 2 < NSTEPS) LOAD_TILE((k + 2) * BK);
    COMPUTE_TILE(rbuf);
    SOFT_BARRIER();
  }

#pragma unroll
  for (int ni = 0; ni < 4; ++ni) {
    const int col = n0 + wn + (ni << 4) + (lane & 15);
    const float bv = bias[col];
#pragma unroll
    for (int mi = 0; mi < 4; ++mi) {
      const int r0e = m0 + wm + (mi << 4) + ((lane >> 4) << 2);
#pragma unroll
      for (int j = 0; j < 4; ++j)
        Y[(size_t)(r0e + j) * N_TOTAL + col] = acc[mi][ni][j] + bv;
    }
  }
}

extern "C" void kernel_launch(void* const* d_in, const int* in_sizes, int n_in,
                              void* d_out, int out_size, void* d_ws, size_t ws_size,
                              hipStream_t stream) {
  const float* X = (const float*)d_in[0];
  const float* Rm = (const float*)d_in[1];
  const float* Im = (const float*)d_in[2];
  const float* Jm = (const float*)d_in[3];
  const float* Km = (const float*)d_in[4];
  const float* bias = (const float*)d_in[5];
  float* Y = (float*)d_out;

  if (ws_size >= (size_t)(4 * 256 * 256 * 2)) {  // 512 KB frag-major bf16 B
    ushort* ws = (ushort*)d_ws;
    conv_b<<<dim3(128), dim3(256), 0, stream>>>(Rm, Im, Jm, Km, ws);
    dim3 grid((M_TOTAL / BM3) * (N_TOTAL / BN3));  // 1024
    qlin_gemm3<<<grid, dim3(NT3), 0, stream>>>(X, ws, bias, Y);
  } else {
    dim3 grid((M_TOTAL / BM) * (N_TOTAL / BN));    // 2048
    qlin_gemm<<<grid, dim3(NTHREADS), 0, stream>>>(X, Rm, Im, Jm, Km, bias, Y);
  }
}

// Round 9
// 180.597 us; speedup vs baseline: 2.1487x; 2.1487x over previous
//
#include <hip/hip_runtime.h>
#include <hip/hip_bf16.h>

typedef __attribute__((ext_vector_type(4))) float f32x4;
typedef __attribute__((ext_vector_type(4))) uint u32x4;
typedef __attribute__((ext_vector_type(8))) short bf16x8;

#define M_TOTAL 32768
#define N_TOTAL 1024
#define K_TOTAL 1024

__device__ __forceinline__ uint pk2(float a, float b) {
  __hip_bfloat162 h = __float22bfloat162_rn(make_float2(a, b));  // v_cvt_pk_bf16_f32
  uint u;
  __builtin_memcpy(&u, &h, 4);
  return u;
}

// Non-draining barrier (T4): ds visibility via lgkmcnt(0); global prefetches
// stay in flight across it (counted vmcnt at consumption). Rule #18 pinning.
#define SOFT_BARRIER() do {                                                   \
    __builtin_amdgcn_sched_barrier(0);                                        \
    asm volatile("s_waitcnt lgkmcnt(0)" ::: "memory");                        \
    __builtin_amdgcn_s_barrier();                                             \
    __builtin_amdgcn_sched_barrier(0);                                        \
  } while (0)

// ===========================================================================
// Pre-kernel: convert 4x 256x256 f32 S-matrices to fragment-major bf16 in ws.
// Fragment (si, cb, kb): 64 lanes x 16B contiguous; lane l holds
// S[cb*16 + (l&15)][kb*32 + (l>>4)*8 .. +7]  (matches MFMA frag layout).
// Verified correct in rounds 7/8 (absmax 0.03125).
// ===========================================================================
__global__ __launch_bounds__(256) void conv_b(
    const float* __restrict__ Rm, const float* __restrict__ Im,
    const float* __restrict__ Jm, const float* __restrict__ Km,
    ushort* __restrict__ ws)
{
  const int slot = blockIdx.x * 256 + threadIdx.x;  // 0..32767
  const int lane = slot & 63;
  const int kb = (slot >> 6) & 7;
  const int cb = (slot >> 9) & 15;
  const int si = slot >> 13;
  const float* S = (si == 0) ? Rm : (si == 1) ? Im : (si == 2) ? Jm : Km;
  const float* p = S + (cb * 16 + (lane & 15)) * 256 + kb * 32 + (lane >> 4) * 8;
  f32x4 lo = *(const f32x4*)p;
  f32x4 hi = *(const f32x4*)(p + 4);
  u32x4 v;
  v[0] = pk2(lo[0], lo[1]); v[1] = pk2(lo[2], lo[3]);
  v[2] = pk2(hi[0], hi[1]); v[3] = pk2(hi[2], hi[3]);
  *(u32x4*)(ws + (size_t)slot * 8) = v;
}

// ===========================================================================
// Main kernel v4: 128x128 block tile, 4 waves (2x2), wave tile 64x64
// (acc = 64 VGPR). 256-thread blocks -> occupancy granularity 1 wave/SIMD;
// launch_bounds(256,3) caps VGPR at ~170 (no forced spill; round-8 lesson:
// (512,4)'s 128-cap spilled acc -> 800 MB scratch, 388 us).
// A: f32 -> reg -> cvt -> swizzled LDS (32 KB dbuf). B: frag-direct from ws.
// ===========================================================================
#define BM4 128
#define BN4 128
#define BK4 64
#define NT4 256
#define NSTEPS4 (K_TOTAL / BK4)

#define LOAD_A4(kk) do {                                                      \
    _Pragma("unroll")                                                         \
    for (int cc = 0; cc < 4; ++cc) {                                          \
      const float* pa_ = X + (size_t)(m0 + r0 + 32 * cc) * K_TOTAL + (kk) + k0;\
      rA[2 * cc]     = *(const f32x4*)pa_;                                    \
      rA[2 * cc + 1] = *(const f32x4*)(pa_ + 4);                              \
    }                                                                         \
  } while (0)

#define COMMIT_A4(dst) do {                                                   \
    _Pragma("unroll")                                                         \
    for (int cc = 0; cc < 4; ++cc) {                                          \
      u32x4 va_;                                                              \
      va_[0] = pk2(rA[2 * cc][0], rA[2 * cc][1]);                             \
      va_[1] = pk2(rA[2 * cc][2], rA[2 * cc][3]);                             \
      va_[2] = pk2(rA[2 * cc + 1][0], rA[2 * cc + 1][1]);                     \
      va_[3] = pk2(rA[2 * cc + 1][2], rA[2 * cc + 1][3]);                     \
      *(u32x4*)((dst) + sbase + 4096 * cc) = va_;                             \
    }                                                                         \
  } while (0)

// Load 8 B-frags (2 ks x 4 ni) for K-step kk; sign via bf16 sign-bit XOR
// (block-uniform; commutes with RNE cvt -> bit-identical numerics).
#define LOAD_B4(kk) do {                                                      \
    const int bsel_ = (kk) >> 8;                                              \
    const int si_ = a_idx ^ bsel_;                                            \
    const int kbq_ = ((kk) & 255) >> 5;                                       \
    const ushort* fb_ = WS + ((size_t)((si_ * 16 + cb0) * 8 + kbq_)) * 512    \
                        + lane * 8;                                           \
    _Pragma("unroll")                                                         \
    for (int ks = 0; ks < 2; ++ks)                                            \
      _Pragma("unroll")                                                       \
      for (int ni = 0; ni < 4; ++ni)                                          \
        bq[ks * 4 + ni] = *(const bf16x8*)(fb_ + (ni * 8 + ks) * 512);        \
    if ((0x284Eu >> ((a_idx << 2) | bsel_)) & 1u) {                           \
      _Pragma("unroll")                                                       \
      for (int f = 0; f < 8; ++f) {                                           \
        u32x4 u_ = __builtin_bit_cast(u32x4, bq[f]);                          \
        u_[0] ^= 0x80008000u; u_[1] ^= 0x80008000u;                           \
        u_[2] ^= 0x80008000u; u_[3] ^= 0x80008000u;                           \
        bq[f] = __builtin_bit_cast(bf16x8, u_);                               \
      }                                                                       \
    }                                                                         \
  } while (0)

#define COMPUTE4(src) do {                                                    \
    _Pragma("unroll")                                                         \
    for (int ks = 0; ks < 2; ++ks) {                                          \
      const int kb_ = (ks << 6) + fkb;                                        \
      _Pragma("unroll")                                                       \
      for (int mi = 0; mi < 4; ++mi) {                                        \
        const int row_ = frow_a0 + (mi << 4);                                 \
        bf16x8 af_ = *(const bf16x8*)((src) + row_ * (BK4 * 2)                \
                                      + (kb_ ^ ((row_ & 7) << 4)));           \
        _Pragma("unroll")                                                     \
        for (int ni = 0; ni < 4; ++ni)                                        \
          acc[mi][ni] = __builtin_amdgcn_mfma_f32_16x16x32_bf16(              \
              af_, bq[ks * 4 + ni], acc[mi][ni], 0, 0, 0);                    \
      }                                                                       \
    }                                                                         \
  } while (0)

__global__ __launch_bounds__(NT4, 3) void qlin_gemm4(
    const float* __restrict__ X, const ushort* __restrict__ WS,
    const float* __restrict__ bias, float* __restrict__ Y)
{
  // 2048 blocks = 256 m-blocks x 8 n-blocks; XCD-bijective swizzle
  // (2048%8==0), n fastest so an XCD chunk shares A-panels in its L2.
  const int per = ((M_TOTAL / BM4) * (N_TOTAL / BN4)) >> 3;  // 256
  const int bid = (int)blockIdx.x;
  const int swz = (bid & 7) * per + (bid >> 3);
  const int m0 = (swz >> 3) * BM4;
  const int nblk = swz & 7;
  const int n0 = nblk * BN4;
  const int a_idx = nblk >> 1;  // source quadrant row (128-col blocks)

  const int tid = (int)threadIdx.x;
  const int lane = tid & 63;
  const int wave = tid >> 6;
  const int wm = (wave >> 1) << 6;  // wave row origin: 0/64
  const int wn = (wave & 1) << 6;   // wave col origin: 0/64
  // col-frag base within the 256-col source matrix (16-col units):
  const int cb0 = ((nblk & 1) << 3) + ((wave & 1) << 2);

  __shared__ __align__(16) ushort smA[2 * BM4 * BK4];  // 32 KB dbuf
  char* const cS = (char*)smA;

  // A staging: thread stages 32 elems = 4 chunks of 8; rows r0 + 32*cc.
  const int r0 = tid >> 3;        // 0..31
  const int k0 = (tid & 7) << 3;  // 0..56
  const int sbase = r0 * (BK4 * 2) + ((k0 * 2) ^ ((r0 & 7) << 4));

  f32x4 rA[8];
  bf16x8 bq[8];
  f32x4 acc[4][4];
#pragma unroll
  for (int i = 0; i < 4; ++i)
#pragma unroll
    for (int j = 0; j < 4; ++j) acc[i][j] = (f32x4)(0.0f);

  const int frow_a0 = wm + (lane & 15);
  const int fkb = (lane >> 4) << 4;

  // prologue
  LOAD_A4(0);
  COMMIT_A4(cS);
  LOAD_A4(BK4);
  SOFT_BARRIER();

  // main loop: commit(k+1 from rA) -> LOAD_B(k) -> prefetch A(k+2) ->
  // compute(k) waits B at counted vmcnt (A prefetch stays in flight).
#pragma unroll 1
  for (int k = 0; k < NSTEPS4; ++k) {
    char* const rbuf = cS + ((k & 1) << 14);
    char* const wbuf = cS + (((k + 1) & 1) << 14);
    COMMIT_A4(wbuf);                              // cvt rA(k+1) -> LDS
    LOAD_B4(k * BK4);                             // 8 frag loads (L2)
    if (k + 2 < NSTEPS4) LOAD_A4((k + 2) * BK4);  // prefetch A(k+2)
    COMPUTE4(rbuf);                               // 8 ds_read + 32 MFMA
    SOFT_BARRIER();
  }

  // epilogue: C/D layout col = lane&15, row = (lane>>4)*4 + reg  [m89-verified]
#pragma unroll
  for (int ni = 0; ni < 4; ++ni) {
    const int col = n0 + wn + (ni << 4) + (lane & 15);
    const float bv = bias[col];
#pragma unroll
    for (int mi = 0; mi < 4; ++mi) {
      const int r0e = m0 + wm + (mi << 4) + ((lane >> 4) << 2);
#pragma unroll
      for (int j = 0; j < 4; ++j)
        Y[(size_t)(r0e + j) * N_TOTAL + col] = acc[mi][ni][j] + bv;
    }
  }
}

// ===========================================================================
// Fallback (proven round-6 kernel, 126 us) — used only if ws_size < 512 KB.
// ===========================================================================
#define BM 128
#define BN 128
#define BK 64
#define NTHREADS 256
#define NSTEPS (K_TOTAL / BK)

#define LOAD_TILE(kk) do {                                                    \
    const int si_ = a_idx ^ ((kk) >> 8);                                      \
    const float* Bsrc_ = (si_ == 0) ? Rm : (si_ == 1) ? Im                    \
                       : (si_ == 2) ? Jm : Km;                                \
    const int kloc_ = (kk) & 255;                                             \
    _Pragma("unroll")                                                         \
    for (int cc = 0; cc < 4; ++cc) {                                          \
      const float* pa_ = X + (size_t)(m0 + r0 + 32 * cc) * K_TOTAL + (kk) + k0;\
      rA[2 * cc]     = *(const f32x4*)pa_;                                    \
      rA[2 * cc + 1] = *(const f32x4*)(pa_ + 4);                              \
      const float* pb_ = Bsrc_ + (o_src + r0 + 32 * cc) * 256 + kloc_ + k0;   \
      rB[2 * cc]     = *(const f32x4*)pb_;                                    \
      rB[2 * cc + 1] = *(const f32x4*)(pb_ + 4);                              \
    }                                                                         \
  } while (0)

#define COMMIT_TILE(kk, dst) do {                                             \
    const uint neg_ = (0x284Eu >> ((a_idx << 2) | ((kk) >> 8))) & 1u;         \
    _Pragma("unroll")                                                         \
    for (int cc = 0; cc < 4; ++cc) {                                          \
      u32x4 va_;                                                              \
      va_[0] = pk2(rA[2 * cc][0], rA[2 * cc][1]);                             \
      va_[1] = pk2(rA[2 * cc][2], rA[2 * cc][3]);                             \
      va_[2] = pk2(rA[2 * cc + 1][0], rA[2 * cc + 1][1]);                     \
      va_[3] = pk2(rA[2 * cc + 1][2], rA[2 * cc + 1][3]);                     \
      *(u32x4*)((dst) + sbase + 4096 * cc) = va_;                             \
    }                                                                         \
    if (neg_) {                                                               \
      _Pragma("unroll")                                                       \
      for (int cc = 0; cc < 4; ++cc) {                                        \
        u32x4 vb_;                                                            \
        vb_[0] = pk2(-rB[2 * cc][0], -rB[2 * cc][1]);                         \
        vb_[1] = pk2(-rB[2 * cc][2], -rB[2 * cc][3]);                         \
        vb_[2] = pk2(-rB[2 * cc + 1][0], -rB[2 * cc + 1][1]);                 \
        vb_[3] = pk2(-rB[2 * cc + 1][2], -rB[2 * cc + 1][3]);                 \
        *(u32x4*)((dst) + 16384 + sbase + 4096 * cc) = vb_;                   \
      }                                                                       \
    } else {                                                                  \
      _Pragma("unroll")                                                       \
      for (int cc = 0; cc < 4; ++cc) {                                        \
        u32x4 vb_;                                                            \
        vb_[0] = pk2(rB[2 * cc][0], rB[2 * cc][1]);                           \
        vb_[1] = pk2(rB[2 * cc][2], rB[2 * cc][3]);                           \
        vb_[2] = pk2(rB[2 * cc + 1][0], rB[2 * cc + 1][1]);                   \
        vb_[3] = pk2(rB[2 * cc + 1][2], rB[2 * cc + 1][3]);                   \
        *(u32x4*)((dst) + 16384 + sbase + 4096 * cc) = vb_;                   \
      }                                                                       \
    }                                                                         \
  } while (0)

#define COMPUTE_TILE(src) do {                                                \
    _Pragma("unroll")                                                         \
    for (int ks = 0; ks < 2; ++ks) {                                          \
      const int kb_ = (ks << 6) + fkb;                                        \
      bf16x8 af_[4], bf_[4];                                                  \
      _Pragma("unroll")                                                       \
      for (int mi = 0; mi < 4; ++mi) {                                        \
        const int row_ = frow_a0 + (mi << 4);                                 \
        af_[mi] = *(const bf16x8*)((src) + row_ * (BK * 2)                    \
                                   + (kb_ ^ ((row_ & 7) << 4)));              \
      }                                                                       \
      _Pragma("unroll")                                                       \
      for (int ni = 0; ni < 4; ++ni) {                                        \
        const int row_ = frow_b0 + (ni << 4);                                 \
        bf_[ni] = *(const bf16x8*)((src) + 16384 + row_ * (BK * 2)            \
                                   + (kb_ ^ ((row_ & 7) << 4)));              \
      }                                                                       \
      _Pragma("unroll")                                                       \
      for (int mi = 0; mi < 4; ++mi)                                          \
        _Pragma("unroll")                                                     \
        for (int ni = 0; ni < 4; ++ni)                                        \
          acc[mi][ni] = __builtin_amdgcn_mfma_f32_16x16x32_bf16(              \
              af_[mi], bf_[ni], acc[mi][ni], 0, 0, 0);                        \
    }                                                                         \
  } while (0)

__global__ __launch_bounds__(NTHREADS, 2) void qlin_gemm(
    const float* __restrict__ X, const float* __restrict__ Rm,
    const float* __restrict__ Im, const float* __restrict__ Jm,
    const float* __restrict__ Km, const float* __restrict__ bias,
    float* __restrict__ Y)
{
  const int per = ((M_TOTAL / BM) * (N_TOTAL / BN)) >> 3;
  const int bid = (int)blockIdx.x;
  const int swz = (bid & 7) * per + (bid >> 3);
  const int m0 = (swz >> 3) * BM;
  const int n0 = (swz & 7) * BN;

  const int tid = (int)threadIdx.x;
  const int lane = tid & 63;
  const int wave = tid >> 6;
  const int wm = (wave >> 1) << 6;
  const int wn = (wave & 1) << 6;

  __shared__ __align__(16) ushort sm[2 * 2 * BM * BK];
  char* const cS = (char*)sm;

  const int a_idx = n0 >> 8;
  const int o_src = n0 & 255;

  const int r0 = tid >> 3;
  const int k0 = (tid & 7) << 3;
  const int sbase = r0 * (BK * 2) + ((k0 * 2) ^ ((r0 & 7) << 4));

  f32x4 rA[8], rB[8];
  f32x4 acc[4][4];
#pragma unroll
  for (int i = 0; i < 4; ++i)
#pragma unroll
    for (int j = 0; j < 4; ++j) acc[i][j] = (f32x4)(0.0f);

  const int frow_a0 = wm + (lane & 15);
  const int frow_b0 = wn + (lane & 15);
  const int fkb = (lane >> 4) << 4;

  LOAD_TILE(0);
  COMMIT_TILE(0, cS);
  LOAD_TILE(BK);
  SOFT_BARRIER();

#pragma unroll 1
  for (int k = 0; k < NSTEPS; ++k) {
    char* const rbuf = cS + ((k & 1) << 15);
    char* const wbuf = cS + (((k + 1) & 1) << 15);
    if (k + 1 < NSTEPS) COMMIT_TILE((k + 1) * BK, wbuf);
    if (k + 2 < NSTEPS) LOAD_TILE((k + 2) * BK);
    COMPUTE_TILE(rbuf);
    SOFT_BARRIER();
  }

#pragma unroll
  for (int ni = 0; ni < 4; ++ni) {
    const int col = n0 + wn + (ni << 4) + (lane & 15);
    const float bv = bias[col];
#pragma unroll
    for (int mi = 0; mi < 4; ++mi) {
      const int r0e = m0 + wm + (mi << 4) + ((lane >> 4) << 2);
#pragma unroll
      for (int j = 0; j < 4; ++j)
        Y[(size_t)(r0e + j) * N_TOTAL + col] = acc[mi][ni][j] + bv;
    }
  }
}

extern "C" void kernel_launch(void* const* d_in, const int* in_sizes, int n_in,
                              void* d_out, int out_size, void* d_ws, size_t ws_size,
                              hipStream_t stream) {
  const float* X = (const float*)d_in[0];
  const float* Rm = (const float*)d_in[1];
  const float* Im = (const float*)d_in[2];
  const float* Jm = (const float*)d_in[3];
  const float* Km = (const float*)d_in[4];
  const float* bias = (const float*)d_in[5];
  float* Y = (float*)d_out;

  if (ws_size >= (size_t)(4 * 256 * 256 * 2)) {  // 512 KB frag-major bf16 B
    ushort* ws = (ushort*)d_ws;
    conv_b<<<dim3(128), dim3(256), 0, stream>>>(Rm, Im, Jm, Km, ws);
    dim3 grid((M_TOTAL / BM4) * (N_TOTAL / BN4));  // 2048
    qlin_gemm4<<<grid, dim3(NT4), 0, stream>>>(X, ws, bias, Y);
  } else {
    dim3 grid((M_TOTAL / BM) * (N_TOTAL / BN));    // 2048
    qlin_gemm<<<grid, dim3(NTHREADS), 0, stream>>>(X, Rm, Im, Jm, Km, bias, Y);
  }
}

// Round 10
// 131.611 us; speedup vs baseline: 2.9484x; 1.3722x over previous
//
#include <hip/hip_runtime.h>
#include <hip/hip_bf16.h>

typedef __attribute__((ext_vector_type(4))) float f32x4;
typedef __attribute__((ext_vector_type(4))) uint u32x4;
typedef __attribute__((ext_vector_type(8))) short bf16x8;

#define M_TOTAL 32768
#define N_TOTAL 1024
#define K_TOTAL 1024

__device__ __forceinline__ uint pk2(float a, float b) {
  __hip_bfloat162 h = __float22bfloat162_rn(make_float2(a, b));  // v_cvt_pk_bf16_f32
  uint u;
  __builtin_memcpy(&u, &h, 4);
  return u;
}

// Non-draining barrier (fallback kernels only).
#define SOFT_BARRIER() do {                                                   \
    __builtin_amdgcn_sched_barrier(0);                                        \
    asm volatile("s_waitcnt lgkmcnt(0)" ::: "memory");                        \
    __builtin_amdgcn_s_barrier();                                             \
    __builtin_amdgcn_sched_barrier(0);                                        \
  } while (0)

// ===========================================================================
// Pass 1a: X (32768x1024 f32) -> fragment-major bf16 in wsx (64 MB).
// Frag (fm, kb): 1 KB; lane l holds X[fm*16 + (l&15)][kb*32 + (l>>4)*8 .. +7].
// Reads: 16x128B fully-used segments/wave; writes: 1 KB coalesced/wave.
// ===========================================================================
__global__ __launch_bounds__(256) void conv_x(
    const float* __restrict__ X, ushort* __restrict__ wsx)
{
  const int g = blockIdx.x * 256 + (int)threadIdx.x;
  const int wid = g >> 6;   // 0..65535 = (fm 0..2047, kb 0..31)
  const int lane = g & 63;
  const int fm = wid >> 5;
  const int kb = wid & 31;
  const float* p = X + (size_t)(fm * 16 + (lane & 15)) * K_TOTAL
                     + kb * 32 + (lane >> 4) * 8;
  f32x4 lo = *(const f32x4*)p;
  f32x4 hi = *(const f32x4*)(p + 4);
  u32x4 v;
  v[0] = pk2(lo[0], lo[1]); v[1] = pk2(lo[2], lo[3]);
  v[2] = pk2(hi[0], hi[1]); v[3] = pk2(hi[2], hi[3]);
  *(u32x4*)(wsx + (size_t)wid * 512 + lane * 8) = v;
}

// ===========================================================================
// Pass 1b: 4x 256x256 f32 S-matrices -> fragment-major bf16 (512 KB).
// Verified rounds 7-9 (absmax 0.03125).
// ===========================================================================
__global__ __launch_bounds__(256) void conv_b(
    const float* __restrict__ Rm, const float* __restrict__ Im,
    const float* __restrict__ Jm, const float* __restrict__ Km,
    ushort* __restrict__ ws)
{
  const int slot = blockIdx.x * 256 + (int)threadIdx.x;  // 0..32767
  const int lane = slot & 63;
  const int kb = (slot >> 6) & 7;
  const int cb = (slot >> 9) & 15;
  const int si = slot >> 13;
  const float* S = (si == 0) ? Rm : (si == 1) ? Im : (si == 2) ? Jm : Km;
  const float* p = S + (cb * 16 + (lane & 15)) * 256 + kb * 32 + (lane >> 4) * 8;
  f32x4 lo = *(const f32x4*)p;
  f32x4 hi = *(const f32x4*)(p + 4);
  u32x4 v;
  v[0] = pk2(lo[0], lo[1]); v[1] = pk2(lo[2], lo[3]);
  v[2] = pk2(hi[0], hi[1]); v[3] = pk2(hi[2], hi[3]);
  *(u32x4*)(ws + (size_t)slot * 8) = v;
}

// ===========================================================================
// Pass 2: fragment-streaming GEMM. NO LDS, NO barriers, NO cvt.
// Block = 64m x 256n, 4 independent waves (64x64 each). Per K-step(64):
// 16 coalesced frag loads + 32 MFMA; register double-buffer (A0/B0 | A1/B1)
// -> compiler emits counted vmcnt(16) before MFMA (T4 with no barrier to
// defeat it). Sign via in-register bf16 sign-bit XOR (commutes with RNE).
// ===========================================================================
#define LOADF(kk, AF, BF) do {                                                \
    const int kbf0_ = (kk) >> 5;                                              \
    _Pragma("unroll")                                                         \
    for (int mi = 0; mi < 4; ++mi)                                            \
      _Pragma("unroll")                                                       \
      for (int ks = 0; ks < 2; ++ks)                                          \
        AF[mi * 2 + ks] = *(const bf16x8*)(                                   \
            WSX + (size_t)((fm0 + mi) * 32 + kbf0_ + ks) * 512 + lane * 8);   \
    const int si_ = a_idx ^ ((kk) >> 8);                                      \
    const int kbq_ = ((kk) & 255) >> 5;                                       \
    _Pragma("unroll")                                                         \
    for (int ks = 0; ks < 2; ++ks)                                            \
      _Pragma("unroll")                                                       \
      for (int ni = 0; ni < 4; ++ni)                                          \
        BF[ks * 4 + ni] = *(const bf16x8*)(                                   \
            WSB + (size_t)((si_ * 16 + cb0 + ni) * 8 + kbq_ + ks) * 512       \
            + lane * 8);                                                      \
  } while (0)

#define SGNFIX(kk, BF) do {                                                   \
    if ((0x284Eu >> ((a_idx << 2) | ((kk) >> 8))) & 1u) {                     \
      _Pragma("unroll")                                                       \
      for (int f = 0; f < 8; ++f) {                                           \
        u32x4 u_ = __builtin_bit_cast(u32x4, BF[f]);                          \
        u_[0] ^= 0x80008000u; u_[1] ^= 0x80008000u;                           \
        u_[2] ^= 0x80008000u; u_[3] ^= 0x80008000u;                           \
        BF[f] = __builtin_bit_cast(bf16x8, u_);                               \
      }                                                                       \
    }                                                                         \
  } while (0)

#define MFMAS(AF, BF) do {                                                    \
    _Pragma("unroll")                                                         \
    for (int ks = 0; ks < 2; ++ks)                                            \
      _Pragma("unroll")                                                       \
      for (int mi = 0; mi < 4; ++mi)                                          \
        _Pragma("unroll")                                                     \
        for (int ni = 0; ni < 4; ++ni)                                        \
          acc[mi][ni] = __builtin_amdgcn_mfma_f32_16x16x32_bf16(              \
              AF[mi * 2 + ks], BF[ks * 4 + ni], acc[mi][ni], 0, 0, 0);        \
  } while (0)

__global__ __launch_bounds__(256, 2) void qlin_gemm5(
    const ushort* __restrict__ WSX, const ushort* __restrict__ WSB,
    const float* __restrict__ bias, float* __restrict__ Y)
{
  // 2048 blocks = 512 m-blocks x 4 n-blocks; XCD-bijective swizzle
  // (2048%8==0), n fastest so an XCD chunk shares X-frags in its L2.
  const int per = 2048 >> 3;  // 256
  const int bid = (int)blockIdx.x;
  const int swz = (bid & 7) * per + (bid >> 3);
  const int mblk = swz >> 2;       // 0..511
  const int a_idx = swz & 3;       // n-quadrant (256 cols each)
  const int n0 = a_idx << 8;
  const int m0 = mblk << 6;
  const int fm0 = mblk << 2;

  const int tid = (int)threadIdx.x;
  const int lane = tid & 63;
  const int w = tid >> 6;          // wave 0..3 -> cols n0 + w*64
  const int cb0 = w << 2;          // col-frag base in source matrix

  bf16x8 A0[8], B0[8], A1[8], B1[8];
  f32x4 acc[4][4];
#pragma unroll
  for (int i = 0; i < 4; ++i)
#pragma unroll
    for (int j = 0; j < 4; ++j) acc[i][j] = (f32x4)(0.0f);

  LOADF(0, A0, B0);
#pragma unroll 1
  for (int k = 0; k < 16; k += 2) {
    const int kk0 = k << 6;
    if (k + 1 < 16) LOADF(kk0 + 64, A1, B1);   // prefetch (stays in flight)
    SGNFIX(kk0, B0);
    MFMAS(A0, B0);                             // waits vmcnt(16): only own regs
    if (k + 2 < 16) LOADF(kk0 + 128, A0, B0);
    SGNFIX(kk0 + 64, B1);
    MFMAS(A1, B1);
  }

  // epilogue: C/D layout col = lane&15, row = (lane>>4)*4 + reg  [m89-verified]
#pragma unroll
  for (int ni = 0; ni < 4; ++ni) {
    const int col = n0 + (w << 6) + (ni << 4) + (lane & 15);
    const float bv = bias[col];
#pragma unroll
    for (int mi = 0; mi < 4; ++mi) {
      const int r0e = m0 + (mi << 4) + ((lane >> 4) << 2);
#pragma unroll
      for (int j = 0; j < 4; ++j)
        Y[(size_t)(r0e + j) * N_TOTAL + col] = acc[mi][ni][j] + bv;
    }
  }
}

// ===========================================================================
// Mid-tier (round-7 champion, 116.6 us): 256x256 tile, B frag-direct, A LDS.
// Used if ws fits B-frags (512 KB) but not X-frags.
// ===========================================================================
#define BM2 256
#define BN2 256
#define BK2 64
#define NT2 512
#define NSTEPS2 (K_TOTAL / BK2)

#define LOAD_A2(kk) do {                                                      \
    _Pragma("unroll")                                                         \
    for (int cc = 0; cc < 4; ++cc) {                                          \
      const float* pa_ = X + (size_t)(m0 + r0 + 64 * cc) * K_TOTAL + (kk) + k0;\
      rA[2 * cc]     = *(const f32x4*)pa_;                                    \
      rA[2 * cc + 1] = *(const f32x4*)(pa_ + 4);                              \
    }                                                                         \
  } while (0)

#define COMMIT_A2(dst) do {                                                   \
    _Pragma("unroll")                                                         \
    for (int cc = 0; cc < 4; ++cc) {                                          \
      u32x4 va_;                                                              \
      va_[0] = pk2(rA[2 * cc][0], rA[2 * cc][1]);                             \
      va_[1] = pk2(rA[2 * cc][2], rA[2 * cc][3]);                             \
      va_[2] = pk2(rA[2 * cc + 1][0], rA[2 * cc + 1][1]);                     \
      va_[3] = pk2(rA[2 * cc + 1][2], rA[2 * cc + 1][3]);                     \
      *(u32x4*)((dst) + sbase + 8192 * cc) = va_;                             \
    }                                                                         \
  } while (0)

#define LOAD_B2(kk) do {                                                      \
    const int bsel_ = (kk) >> 8;                                              \
    const int si_ = a_idx ^ bsel_;                                            \
    const int kbq_ = ((kk) & 255) >> 5;                                       \
    const ushort* fb_ = WS + ((size_t)((si_ * 16 + wc4) * 8 + kbq_)) * 512    \
                        + lane * 8;                                           \
    _Pragma("unroll")                                                         \
    for (int ks = 0; ks < 2; ++ks)                                            \
      _Pragma("unroll")                                                       \
      for (int ni = 0; ni < 4; ++ni)                                          \
        bq[ks * 4 + ni] = *(const bf16x8*)(fb_ + (ni * 8 + ks) * 512);        \
    if ((0x284Eu >> ((a_idx << 2) | bsel_)) & 1u) {                           \
      _Pragma("unroll")                                                       \
      for (int f = 0; f < 8; ++f) {                                           \
        u32x4 u_ = __builtin_bit_cast(u32x4, bq[f]);                          \
        u_[0] ^= 0x80008000u; u_[1] ^= 0x80008000u;                           \
        u_[2] ^= 0x80008000u; u_[3] ^= 0x80008000u;                           \
        bq[f] = __builtin_bit_cast(bf16x8, u_);                               \
      }                                                                       \
    }                                                                         \
  } while (0)

#define COMPUTE2(src) do {                                                    \
    _Pragma("unroll")                                                         \
    for (int ks = 0; ks < 2; ++ks) {                                          \
      _Pragma("unroll")                                                       \
      for (int mi = 0; mi < 8; ++mi) {                                        \
        const int row_ = frow_a0 + (mi << 4);                                 \
        const int kb_ = (ks << 6) + fkb;                                      \
        bf16x8 af_ = *(const bf16x8*)((src) + row_ * (BK2 * 2)                \
                                      + (kb_ ^ ((row_ & 7) << 4)));           \
        _Pragma("unroll")                                                     \
        for (int ni = 0; ni < 4; ++ni)                                        \
          acc[mi][ni] = __builtin_amdgcn_mfma_f32_16x16x32_bf16(              \
              af_, bq[ks * 4 + ni], acc[mi][ni], 0, 0, 0);                    \
      }                                                                       \
    }                                                                         \
  } while (0)

__global__ __launch_bounds__(NT2, 2) void qlin_gemm2(
    const float* __restrict__ X, const ushort* __restrict__ WS,
    const float* __restrict__ bias, float* __restrict__ Y)
{
  const int per = ((M_TOTAL / BM2) * (N_TOTAL / BN2)) >> 3;  // 64
  const int bid = (int)blockIdx.x;
  const int swz = (bid & 7) * per + (bid >> 3);
  const int m0 = (swz >> 2) * BM2;
  const int nblk = swz & 3;
  const int n0 = nblk * BN2;
  const int a_idx = nblk;

  const int tid = (int)threadIdx.x;
  const int lane = tid & 63;
  const int wave = tid >> 6;
  const int wm = (wave >> 2) << 7;
  const int wc4 = (wave & 3) << 2;

  __shared__ __align__(16) ushort smA[2 * BM2 * BK2];  // 64 KB dbuf
  char* const cS = (char*)smA;

  const int r0 = tid >> 3;
  const int k0 = (tid & 7) << 3;
  const int sbase = r0 * (BK2 * 2) + ((k0 * 2) ^ ((r0 & 7) << 4));

  f32x4 rA[8];
  bf16x8 bq[8];
  f32x4 acc[8][4];
#pragma unroll
  for (int i = 0; i < 8; ++i)
#pragma unroll
    for (int j = 0; j < 4; ++j) acc[i][j] = (f32x4)(0.0f);

  const int frow_a0 = wm + (lane & 15);
  const int fkb = (lane >> 4) << 4;

  LOAD_A2(0);
  COMMIT_A2(cS);
  LOAD_A2(BK2);
  SOFT_BARRIER();

#pragma unroll 1
  for (int k = 0; k < NSTEPS2; ++k) {
    char* const rbuf = cS + ((k & 1) << 15);
    char* const wbuf = cS + (((k + 1) & 1) << 15);
    COMMIT_A2(wbuf);
    LOAD_B2(k * BK2);
    if (k + 2 < NSTEPS2) LOAD_A2((k + 2) * BK2);
    COMPUTE2(rbuf);
    SOFT_BARRIER();
  }

#pragma unroll
  for (int ni = 0; ni < 4; ++ni) {
    const int col = n0 + (wc4 << 4) + (ni << 4) + (lane & 15);
    const float bv = bias[col];
#pragma unroll
    for (int mi = 0; mi < 8; ++mi) {
      const int r0e = m0 + wm + (mi << 4) + ((lane >> 4) << 2);
#pragma unroll
      for (int j = 0; j < 4; ++j)
        Y[(size_t)(r0e + j) * N_TOTAL + col] = acc[mi][ni][j] + bv;
    }
  }
}

// ===========================================================================
// No-ws fallback (round-6, 126 us).
// ===========================================================================
#define BM 128
#define BN 128
#define BK 64
#define NTHREADS 256
#define NSTEPS (K_TOTAL / BK)

#define LOAD_TILE(kk) do {                                                    \
    const int si_ = a_idx ^ ((kk) >> 8);                                      \
    const float* Bsrc_ = (si_ == 0) ? Rm : (si_ == 1) ? Im                    \
                       : (si_ == 2) ? Jm : Km;                                \
    const int kloc_ = (kk) & 255;                                             \
    _Pragma("unroll")                                                         \
    for (int cc = 0; cc < 4; ++cc) {                                          \
      const float* pa_ = X + (size_t)(m0 + r0 + 32 * cc) * K_TOTAL + (kk) + k0;\
      rA[2 * cc]     = *(const f32x4*)pa_;                                    \
      rA[2 * cc + 1] = *(const f32x4*)(pa_ + 4);                              \
      const float* pb_ = Bsrc_ + (o_src + r0 + 32 * cc) * 256 + kloc_ + k0;   \
      rB[2 * cc]     = *(const f32x4*)pb_;                                    \
      rB[2 * cc + 1] = *(const f32x4*)(pb_ + 4);                              \
    }                                                                         \
  } while (0)

#define COMMIT_TILE(kk, dst) do {                                             \
    const uint neg_ = (0x284Eu >> ((a_idx << 2) | ((kk) >> 8))) & 1u;         \
    _Pragma("unroll")                                                         \
    for (int cc = 0; cc < 4; ++cc) {                                          \
      u32x4 va_;                                                              \
      va_[0] = pk2(rA[2 * cc][0], rA[2 * cc][1]);                             \
      va_[1] = pk2(rA[2 * cc][2], rA[2 * cc][3]);                             \
      va_[2] = pk2(rA[2 * cc + 1][0], rA[2 * cc + 1][1]);                     \
      va_[3] = pk2(rA[2 * cc + 1][2], rA[2 * cc + 1][3]);                     \
      *(u32x4*)((dst) + sbase + 4096 * cc) = va_;                             \
    }                                                                         \
    if (neg_) {                                                               \
      _Pragma("unroll")                                                       \
      for (int cc = 0; cc < 4; ++cc) {                                        \
        u32x4 vb_;                                                            \
        vb_[0] = pk2(-rB[2 * cc][0], -rB[2 * cc][1]);                         \
        vb_[1] = pk2(-rB[2 * cc][2], -rB[2 * cc][3]);                         \
        vb_[2] = pk2(-rB[2 * cc + 1][0], -rB[2 * cc + 1][1]);                 \
        vb_[3] = pk2(-rB[2 * cc + 1][2], -rB[2 * cc + 1][3]);                 \
        *(u32x4*)((dst) + 16384 + sbase + 4096 * cc) = vb_;                   \
      }                                                                       \
    } else {                                                                  \
      _Pragma("unroll")                                                       \
      for (int cc = 0; cc < 4; ++cc) {                                        \
        u32x4 vb_;                                                            \
        vb_[0] = pk2(rB[2 * cc][0], rB[2 * cc][1]);                           \
        vb_[1] = pk2(rB[2 * cc][2], rB[2 * cc][3]);                           \
        vb_[2] = pk2(rB[2 * cc + 1][0], rB[2 * cc + 1][1]);                   \
        vb_[3] = pk2(rB[2 * cc + 1][2], rB[2 * cc + 1][3]);                   \
        *(u32x4*)((dst) + 16384 + sbase + 4096 * cc) = vb_;                   \
      }                                                                       \
    }                                                                         \
  } while (0)

#define COMPUTE_TILE(src) do {                                                \
    _Pragma("unroll")                                                         \
    for (int ks = 0; ks < 2; ++ks) {                                          \
      const int kb_ = (ks << 6) + fkb;                                        \
      bf16x8 af_[4], bf_[4];                                                  \
      _Pragma("unroll")                                                       \
      for (int mi = 0; mi < 4; ++mi) {                                        \
        const int row_ = frow_a0 + (mi << 4);                                 \
        af_[mi] = *(const bf16x8*)((src) + row_ * (BK * 2)                    \
                                   + (kb_ ^ ((row_ & 7) << 4)));              \
      }                                                                       \
      _Pragma("unroll")                                                       \
      for (int ni = 0; ni < 4; ++ni) {                                        \
        const int row_ = frow_b0 + (ni << 4);                                 \
        bf_[ni] = *(const bf16x8*)((src) + 16384 + row_ * (BK * 2)            \
                                   + (kb_ ^ ((row_ & 7) << 4)));              \
      }                                                                       \
      _Pragma("unroll")                                                       \
      for (int mi = 0; mi < 4; ++mi)                                          \
        _Pragma("unroll")                                                     \
        for (int ni = 0; ni < 4; ++ni)                                        \
          acc[mi][ni] = __builtin_amdgcn_mfma_f32_16x16x32_bf16(              \
              af_[mi], bf_[ni], acc[mi][ni], 0, 0, 0);                        \
    }                                                                         \
  } while (0)

__global__ __launch_bounds__(NTHREADS, 2) void qlin_gemm(
    const float* __restrict__ X, const float* __restrict__ Rm,
    const float* __restrict__ Im, const float* __restrict__ Jm,
    const float* __restrict__ Km, const float* __restrict__ bias,
    float* __restrict__ Y)
{
  const int per = ((M_TOTAL / BM) * (N_TOTAL / BN)) >> 3;
  const int bid = (int)blockIdx.x;
  const int swz = (bid & 7) * per + (bid >> 3);
  const int m0 = (swz >> 3) * BM;
  const int n0 = (swz & 7) * BN;

  const int tid = (int)threadIdx.x;
  const int lane = tid & 63;
  const int wave = tid >> 6;
  const int wm = (wave >> 1) << 6;
  const int wn = (wave & 1) << 6;

  __shared__ __align__(16) ushort sm[2 * 2 * BM * BK];
  char* const cS = (char*)sm;

  const int a_idx = n0 >> 8;
  const int o_src = n0 & 255;

  const int r0 = tid >> 3;
  const int k0 = (tid & 7) << 3;
  const int sbase = r0 * (BK * 2) + ((k0 * 2) ^ ((r0 & 7) << 4));

  f32x4 rA[8], rB[8];
  f32x4 acc[4][4];
#pragma unroll
  for (int i = 0; i < 4; ++i)
#pragma unroll
    for (int j = 0; j < 4; ++j) acc[i][j] = (f32x4)(0.0f);

  const int frow_a0 = wm + (lane & 15);
  const int frow_b0 = wn + (lane & 15);
  const int fkb = (lane >> 4) << 4;

  LOAD_TILE(0);
  COMMIT_TILE(0, cS);
  LOAD_TILE(BK);
  SOFT_BARRIER();

#pragma unroll 1
  for (int k = 0; k < NSTEPS; ++k) {
    char* const rbuf = cS + ((k & 1) << 15);
    char* const wbuf = cS + (((k + 1) & 1) << 15);
    if (k + 1 < NSTEPS) COMMIT_TILE((k + 1) * BK, wbuf);
    if (k + 2 < NSTEPS) LOAD_TILE((k + 2) * BK);
    COMPUTE_TILE(rbuf);
    SOFT_BARRIER();
  }

#pragma unroll
  for (int ni = 0; ni < 4; ++ni) {
    const int col = n0 + wn + (ni << 4) + (lane & 15);
    const float bv = bias[col];
#pragma unroll
    for (int mi = 0; mi < 4; ++mi) {
      const int r0e = m0 + wm + (mi << 4) + ((lane >> 4) << 2);
#pragma unroll
      for (int j = 0; j < 4; ++j)
        Y[(size_t)(r0e + j) * N_TOTAL + col] = acc[mi][ni][j] + bv;
    }
  }
}

extern "C" void kernel_launch(void* const* d_in, const int* in_sizes, int n_in,
                              void* d_out, int out_size, void* d_ws, size_t ws_size,
                              hipStream_t stream) {
  const float* X = (const float*)d_in[0];
  const float* Rm = (const float*)d_in[1];
  const float* Im = (const float*)d_in[2];
  const float* Jm = (const float*)d_in[3];
  const float* Km = (const float*)d_in[4];
  const float* bias = (const float*)d_in[5];
  float* Y = (float*)d_out;

  const size_t needB = (size_t)4 * 256 * 256 * 2;            // 512 KB
  const size_t needX = (size_t)M_TOTAL * K_TOTAL * 2;        // 64 MB

  if (ws_size >= needX + needB) {
    ushort* wsx = (ushort*)d_ws;
    ushort* wsb = wsx + (size_t)M_TOTAL * K_TOTAL;
    conv_x<<<dim3(16384), dim3(256), 0, stream>>>(X, wsx);
    conv_b<<<dim3(128), dim3(256), 0, stream>>>(Rm, Im, Jm, Km, wsb);
    qlin_gemm5<<<dim3(2048), dim3(256), 0, stream>>>(wsx, wsb, bias, Y);
  } else if (ws_size >= needB) {
    ushort* wsb = (ushort*)d_ws;
    conv_b<<<dim3(128), dim3(256), 0, stream>>>(Rm, Im, Jm, Km, wsb);
    qlin_gemm2<<<dim3((M_TOTAL / BM2) * (N_TOTAL / BN2)), dim3(NT2), 0, stream>>>(
        X, wsb, bias, Y);
  } else {
    qlin_gemm<<<dim3((M_TOTAL / BM) * (N_TOTAL / BN)), dim3(NTHREADS), 0, stream>>>(
        X, Rm, Im, Jm, Km, bias, Y);
  }
}